// Round 4
// baseline (1633.533 us; speedup 1.0000x reference)
//
#include <hip/hip_runtime.h>
#include <cmath>

// Problem constants (fixed by reference): grid 65x87 = 5655 voxels, B=8 batches.
#define NXC 65
#define NYC 87
#define VFIX 5655          // NXC*NYC
#define SFIX 45240         // 8*VFIX
#define FDIM 64
#define MAXG 8192          // per-r-bin LDS sort capacity (expected bin max ~450)

// ---------------- kernel 1: cluster assignment + point histogram ----------------
__global__ void k_assign(const float* __restrict__ pos, const int* __restrict__ batch,
                         int* __restrict__ cluster, int* __restrict__ pcount, int N) {
    int i = blockIdx.x * blockDim.x + threadIdx.x;
    if (i >= N) return;
    float px = pos[i * 3 + 0];
    float py = pos[i * 3 + 1];
    int c0 = (int)floorf(px * 0.25f);   // *0.25 == /4.0 exactly (pow2)
    int c1 = (int)floorf(py * 0.25f);
    c0 = min(max(c0, 0), NXC - 1);
    c1 = min(max(c1, 0), NYC - 1);
    int cl = batch[i] * VFIX + c0 * NYC + c1;
    cluster[i] = cl;
    atomicAdd(&pcount[cl], 1);
}

// ---------------- kernel 2: edge histogram over r = cluster[src] ----------------
__global__ void k_ehist(const int* __restrict__ ei, const int* __restrict__ cluster,
                        int* __restrict__ ecount, int E) {
    int e = blockIdx.x * blockDim.x + threadIdx.x;
    if (e >= E) return;
    int r = cluster[ei[e]];
    atomicAdd(&ecount[r], 1);
}

// ---------------- kernel 3: two single-block exclusive scans (writes ofs[0..S]) ----------------
__global__ void k_scan(const int* __restrict__ cnt0, int* __restrict__ ofs0,
                       const int* __restrict__ cnt1, int* __restrict__ ofs1, int S) {
    const int* cnt = blockIdx.x ? cnt1 : cnt0;
    int* ofs = blockIdx.x ? ofs1 : ofs0;
    __shared__ int part[1024];
    int t = threadIdx.x;
    int chunk = (S + 1023) / 1024;
    int lo = t * chunk;
    int hi = min(S, lo + chunk);
    int s = 0;
    for (int i = lo; i < hi; i++) s += cnt[i];
    part[t] = s;
    __syncthreads();
    for (int d = 1; d < 1024; d <<= 1) {
        int v = (t >= d) ? part[t - d] : 0;
        __syncthreads();
        part[t] += v;
        __syncthreads();
    }
    int base = (t == 0) ? 0 : part[t - 1];
    for (int i = lo; i < hi; i++) { ofs[i] = base; base += cnt[i]; }
    if (t == 1023) ofs[S] = part[1023];   // total
}

// ---------------- kernel 4: scatter point indices grouped by cluster ----------------
__global__ void k_pscatter(const int* __restrict__ cluster, const int* __restrict__ pofs,
                           int* __restrict__ pcursor, int* __restrict__ sorted_pt, int N) {
    int i = blockIdx.x * blockDim.x + threadIdx.x;
    if (i >= N) return;
    int cl = cluster[i];
    int p = atomicAdd(&pcursor[cl], 1);
    sorted_pt[pofs[cl] + p] = i;
}

// ---------------- kernel 5: scatter edge c-values (int32) grouped by r ----------------
// cbuf aliases the e1 float region SLOT-FOR-SLOT (cbuf[j] occupies the same
// 4 bytes as e1[j]); k_esort overwrites each bin's slots only after loading
// them into LDS, and bins are byte-disjoint -> no cross-block hazard.
__global__ void k_escatter(const int* __restrict__ ei, const int* __restrict__ cluster,
                           const int* __restrict__ eofs, int* __restrict__ ecursor,
                           int* __restrict__ cbuf, int E) {
    int e = blockIdx.x * blockDim.x + threadIdx.x;
    if (e >= E) return;
    int r = cluster[ei[e]];
    int c = cluster[ei[E + e]];
    int p = atomicAdd(&ecursor[r], 1);
    cbuf[eofs[r] + p] = c;
}

// ---------------- kernel 6: per-cluster pooling (one wave per cluster) ----------------
__global__ __launch_bounds__(64) void k_pool(
        const float* __restrict__ x, const float* __restrict__ pos,
        const int* __restrict__ sorted_pt, const int* __restrict__ pofs,
        float* __restrict__ xo, float* __restrict__ po,
        float* __restrict__ bo, float* __restrict__ mo) {
    int s = blockIdx.x;
    int lane = threadIdx.x;
    int base = pofs[s];
    int n = pofs[s + 1] - base;

    float mx = -INFINITY;
    for (int k = 0; k < n; k++) {
        int p = sorted_pt[base + k];                 // scalar-broadcast read
        mx = fmaxf(mx, x[(long)p * FDIM + lane]);    // 256B coalesced row read
    }
    float sx = 0.f, sy = 0.f, st = 0.f;
    for (int k = lane; k < n; k += 64) {
        int p = sorted_pt[base + k];
        sx += pos[p * 3 + 0];
        sy += pos[p * 3 + 1];
        st += pos[p * 3 + 2];
    }
    for (int o = 32; o > 0; o >>= 1) {
        sx += __shfl_down(sx, o);
        sy += __shfl_down(sy, o);
        st += __shfl_down(st, o);
    }
    if (n == 0) mx = 0.f;
    xo[(long)s * FDIM + lane] = mx;
    if (lane == 0) {
        float inv = 1.f / fmaxf((float)n, 1.f);
        po[s * 3 + 0] = sx * inv;
        po[s * 3 + 1] = sy * inv;
        po[s * 3 + 2] = st * inv;
        bo[s] = (float)(s / VFIX);
        mo[s] = (n > 0) ? 1.f : 0.f;
    }
}

// ---------------- kernel 7: per-r-bin bitonic sort of c (LDS), dedup, emit edges ----------------
__global__ __launch_bounds__(256) void k_esort(
        const int* __restrict__ cbuf, const int* __restrict__ eofs,
        float* __restrict__ e0, float* __restrict__ e1) {
    __shared__ unsigned short sh[MAXG];
    int r = blockIdx.x;
    int base = eofs[r];
    int m = eofs[r + 1] - base;
    if (m <= 0) return;
    int mm = min(m, MAXG);

    int P = 1;
    while (P < mm) P <<= 1;
    for (int i = threadIdx.x; i < P; i += blockDim.x)
        sh[i] = (i < mm) ? (unsigned short)cbuf[base + i] : (unsigned short)0xFFFFu;
    __syncthreads();            // this bin's input fully in LDS

    for (int k = 2; k <= P; k <<= 1) {
        for (int j = k >> 1; j > 0; j >>= 1) {
            for (int i = threadIdx.x; i < P; i += blockDim.x) {
                int l = i ^ j;
                if (l > i) {
                    unsigned short a = sh[i], b = sh[l];
                    bool up = ((i & k) == 0);
                    if (up ? (a > b) : (a < b)) { sh[i] = b; sh[l] = a; }
                }
            }
            __syncthreads();
        }
    }

    float rf = (float)r;
    for (int i = threadIdx.x; i < m; i += blockDim.x) {
        float v0 = -1.f, v1 = -1.f;
        if (i < mm) {
            int c = sh[i];
            bool dup = (i > 0) && ((int)sh[i - 1] == c);
            if (!dup && c != r) { v0 = rf; v1 = (float)c; }
        }
        e0[base + i] = v0;
        e1[base + i] = v1;   // overwrites this bin's own cbuf slots (already in LDS)
    }
}

// ---------------- launch ----------------
extern "C" void kernel_launch(void* const* d_in, const int* in_sizes, int n_in,
                              void* d_out, int out_size, void* d_ws, size_t ws_size,
                              hipStream_t stream) {
    const float* x   = (const float*)d_in[0];
    const float* pos = (const float*)d_in[1];
    const int* batch = (const int*)d_in[2];
    const int* ei    = (const int*)d_in[3];

    const int N = in_sizes[2];          // batch is [N]
    const int E = in_sizes[3] / 2;      // edge_index is [2, E]
    const int S = SFIX;

    // output layout (FLOAT32): x_pool, pos_pool, batch_out, edge_out[2], mask
    // (rounds 1-3 root cause: outputs were written as bf16; d_out is float32 —
    //  the bf16 e0 ramp misplaced into chunk 0 produced the exact observed
    //  absmax 15424-1.195.)
    float* out = (float*)d_out;
    float* xo = out;
    float* po = xo + (size_t)S * FDIM;
    float* bo = po + (size_t)S * 3;
    float* e0 = bo + S;
    float* e1 = e0 + (size_t)E;
    float* mo = e1 + (size_t)E;

    // Staging inside the e0 region (E floats = 32 MB, dead until k_esort):
    //   cluster[N] | sorted_pt[N] | pcount[S] | pcursor[S] | ecount[S] |
    //   ecursor[S] | pofs[S+1]   (~8.9 MB). All consumed before k_esort runs.
    // cbuf (E int32) aliases e1 slot-for-slot. Only eofs must survive INTO
    // k_esort -> d_ws ((S+1)*4 = 181 KB).
    int* cluster   = (int*)e0;
    int* sorted_pt = cluster + N;
    int* cnts      = sorted_pt + N;     // 4*S ints, zeroed below
    int* pcount    = cnts;
    int* pcursor   = cnts + S;
    int* ecount    = cnts + 2 * S;
    int* ecursor   = cnts + 3 * S;
    int* pofs      = cnts + 4 * S;      // S+1 ints
    int* eofs      = (int*)d_ws;        // S+1 ints
    int* cbuf      = (int*)e1;          // E ints, aliases e1 floats slot-for-slot

    hipMemsetAsync(cnts, 0, (size_t)4 * S * sizeof(int), stream);

    k_assign  <<<(N + 255) / 256, 256, 0, stream>>>(pos, batch, cluster, pcount, N);
    k_ehist   <<<(E + 255) / 256, 256, 0, stream>>>(ei, cluster, ecount, E);
    k_scan    <<<2, 1024, 0, stream>>>(pcount, pofs, ecount, eofs, S);
    k_pscatter<<<(N + 255) / 256, 256, 0, stream>>>(cluster, pofs, pcursor, sorted_pt, N);
    k_escatter<<<(E + 255) / 256, 256, 0, stream>>>(ei, cluster, eofs, ecursor, cbuf, E);
    k_pool    <<<S, 64, 0, stream>>>(x, pos, sorted_pt, pofs, xo, po, bo, mo);
    k_esort   <<<S, 256, 0, stream>>>(cbuf, eofs, e0, e1);
}